// Round 1
// baseline (637.033 us; speedup 1.0000x reference)
//
#include <hip/hip_runtime.h>
#include <hip/hip_bf16.h>
#include <stdint.h>

typedef unsigned short u16;
typedef unsigned int u32;
typedef __bf16 bf16x8 __attribute__((ext_vector_type(8)));
typedef float f32x4 __attribute__((ext_vector_type(4)));
typedef u16 u16x4 __attribute__((ext_vector_type(4)));

typedef const __attribute__((address_space(1))) void* gas_ptr;
typedef __attribute__((address_space(3))) void* las_ptr;

#define M_DIM 8192
#define K_DIM 4096
#define N_DIM 4096

__device__ __forceinline__ u16 f32_to_bf16_rne(float f) {
    u32 u = __float_as_uint(f);
    u += 0x7FFFu + ((u >> 16) & 1u);
    return (u16)(u >> 16);
}

// ---- 1) max|W| reduction -> ws[0] as float bits (atomicMax on uint works for non-negative floats)
__global__ void maxabs_kernel(const float* __restrict__ W, u32* __restrict__ out, int n4) {
    int idx = blockIdx.x * blockDim.x + threadIdx.x;
    int stride = gridDim.x * blockDim.x;
    const float4* W4 = (const float4*)W;
    float m = 0.0f;
    for (int i = idx; i < n4; i += stride) {
        float4 v = W4[i];
        m = fmaxf(m, fmaxf(fmaxf(fabsf(v.x), fabsf(v.y)), fmaxf(fabsf(v.z), fabsf(v.w))));
    }
#pragma unroll
    for (int off = 32; off > 0; off >>= 1)
        m = fmaxf(m, __shfl_down(m, off));
    if ((threadIdx.x & 63) == 0)
        atomicMax(out, __float_as_uint(m));
}

// ---- 2) quantize W (K x N, fp32) -> bf16 W^T (N x K). w_q integer in [-127,127]: exact in bf16.
__global__ void quant_transpose_kernel(const float* __restrict__ W, u16* __restrict__ Wt,
                                       const u32* __restrict__ mb) {
    __shared__ u16 tile[32][33];
    const float s_inv = 128.0f / __uint_as_float(*mb);  // 1/s_w, s_w = 2*max/256 = max/128
    int n = blockIdx.x * 32 + threadIdx.x;
#pragma unroll
    for (int r = threadIdx.y; r < 32; r += 8) {
        int k = blockIdx.y * 32 + r;
        float q = rintf(W[(size_t)k * N_DIM + n] * s_inv);  // rintf = round-half-even (matches jnp.round)
        q = fminf(fmaxf(q, -127.0f), 127.0f);
        tile[threadIdx.x][r] = (u16)(__float_as_uint(q) >> 16);  // truncation exact for small ints
    }
    __syncthreads();
    int k_out = blockIdx.y * 32 + threadIdx.x;
#pragma unroll
    for (int r = threadIdx.y; r < 32; r += 8) {
        int n_out = blockIdx.x * 32 + r;
        Wt[(size_t)n_out * K_DIM + k_out] = tile[r][threadIdx.x];
    }
}

// ---- 3) cast xb fp32 -> bf16 (RNE)
__global__ void cast_bf16_kernel(const float* __restrict__ x, u16* __restrict__ y, int n4) {
    int idx = blockIdx.x * blockDim.x + threadIdx.x;
    int stride = gridDim.x * blockDim.x;
    const float4* x4 = (const float4*)x;
    u16x4* y4 = (u16x4*)y;
    for (int i = idx; i < n4; i += stride) {
        float4 v = x4[i];
        u16x4 o;
        o.x = f32_to_bf16_rne(v.x);
        o.y = f32_to_bf16_rne(v.y);
        o.z = f32_to_bf16_rne(v.z);
        o.w = f32_to_bf16_rne(v.w);
        y4[i] = o;
    }
}

// ---- 4) GEMM: out[M][N] = s_w * (A[M][K] @ Bt[N][K]^T) + bias
// 128x128 tile, BK=32, 4 waves, each wave 64x64 via 4x4 of mfma_f32_16x16x32_bf16.
__global__ __launch_bounds__(256) void gemm_kernel(const u16* __restrict__ A,
                                                   const u16* __restrict__ Bt,
                                                   const float* __restrict__ bias,
                                                   const u32* __restrict__ mb,
                                                   float* __restrict__ out) {
    __shared__ u16 As[128 * 32];  // 8 KB, packed row-major (rows of 32 bf16 = 64 B)
    __shared__ u16 Bs[128 * 32];

    const int tid = threadIdx.x;
    const int wave = tid >> 6;
    const int lane = tid & 63;
    const int m0 = blockIdx.y * 128;
    const int n0 = blockIdx.x * 128;

    // staging map: chunk c (1 KB) = rows [16c,16c+16); lane l -> row 16c + l/4, halfword col (l%4)*8
    // LDS dest = base + lane*16 B; (l/4)*64 + (l%4)*16 == 16*l  (exact match, no pad allowed)
    const int lrow = lane >> 2;
    const int lcol = (lane & 3) * 8;

    const u16* Ag0 = A + (size_t)(m0 + wave * 16 + lrow) * K_DIM + lcol;
    const u16* Ag1 = A + (size_t)(m0 + (wave + 4) * 16 + lrow) * K_DIM + lcol;
    const u16* Bg0 = Bt + (size_t)(n0 + wave * 16 + lrow) * K_DIM + lcol;
    const u16* Bg1 = Bt + (size_t)(n0 + (wave + 4) * 16 + lrow) * K_DIM + lcol;

    u16* Asl0 = &As[wave * 512];
    u16* Asl1 = &As[(wave + 4) * 512];
    u16* Bsl0 = &Bs[wave * 512];
    u16* Bsl1 = &Bs[(wave + 4) * 512];

    const int quad = lane >> 4;
    const int l15 = lane & 15;
    const int wm = wave >> 1;  // wave computes rows [wm*64, wm*64+64)
    const int wn = wave & 1;   // cols [wn*64, wn*64+64)

    const float s_w = __uint_as_float(*mb) * (1.0f / 128.0f);

    f32x4 acc[4][4];
#pragma unroll
    for (int i = 0; i < 4; i++)
#pragma unroll
        for (int j = 0; j < 4; j++) acc[i][j] = (f32x4){0.f, 0.f, 0.f, 0.f};

    for (int k0 = 0; k0 < K_DIM; k0 += 32) {
        __syncthreads();  // previous tile's ds_reads done before overwrite
        __builtin_amdgcn_global_load_lds((gas_ptr)(Ag0 + k0), (las_ptr)Asl0, 16, 0, 0);
        __builtin_amdgcn_global_load_lds((gas_ptr)(Ag1 + k0), (las_ptr)Asl1, 16, 0, 0);
        __builtin_amdgcn_global_load_lds((gas_ptr)(Bg0 + k0), (las_ptr)Bsl0, 16, 0, 0);
        __builtin_amdgcn_global_load_lds((gas_ptr)(Bg1 + k0), (las_ptr)Bsl1, 16, 0, 0);
        __syncthreads();  // compiler emits vmcnt(0) drain before s_barrier

        // A frag: A[m=l15][k=quad*8+j] ; B frag (from B^T rows): B[k=quad*8+j][n=l15]
        bf16x8 af[4], bfr[4];
#pragma unroll
        for (int i = 0; i < 4; i++)
            af[i] = *(const bf16x8*)&As[(wm * 64 + i * 16 + l15) * 32 + quad * 8];
#pragma unroll
        for (int j = 0; j < 4; j++)
            bfr[j] = *(const bf16x8*)&Bs[(wn * 64 + j * 16 + l15) * 32 + quad * 8];

#pragma unroll
        for (int i = 0; i < 4; i++)
#pragma unroll
            for (int j = 0; j < 4; j++)
                acc[i][j] = __builtin_amdgcn_mfma_f32_16x16x32_bf16(af[i], bfr[j], acc[i][j], 0, 0, 0);
    }

    // C/D layout: col = lane&15 (N dim), row = quad*4 + reg (M dim)  [m89/m91-verified]
#pragma unroll
    for (int j = 0; j < 4; j++) {
        const int col = n0 + wn * 64 + j * 16 + l15;
        const float bv = bias[col];
#pragma unroll
        for (int i = 0; i < 4; i++) {
            const int row = m0 + wm * 64 + i * 16 + quad * 4;
            float* op = out + (size_t)row * N_DIM + col;
#pragma unroll
            for (int r = 0; r < 4; r++) op[(size_t)r * N_DIM] = s_w * acc[i][j][r] + bv;
        }
    }
}

extern "C" void kernel_launch(void* const* d_in, const int* in_sizes, int n_in,
                              void* d_out, int out_size, void* d_ws, size_t ws_size,
                              hipStream_t stream) {
    const float* xb = (const float*)d_in[0];  // 8192 x 4096 fp32
    const float* W = (const float*)d_in[1];   // 4096 x 4096 fp32
    const float* b = (const float*)d_in[2];   // 4096 fp32
    float* out = (float*)d_out;               // 8192 x 4096 fp32

    // workspace layout: [0,4): maxabs bits | [256, 256+64M): xb bf16 | then W^T bf16 (32M)
    u32* mb = (u32*)d_ws;
    u16* xb_bf = (u16*)((char*)d_ws + 256);
    u16* wqt = (u16*)((char*)d_ws + 256 + (size_t)M_DIM * K_DIM * 2);

    hipMemsetAsync(d_ws, 0, 4, stream);  // ws is re-poisoned 0xAA before every call
    maxabs_kernel<<<1024, 256, 0, stream>>>(W, mb, (K_DIM * N_DIM) / 4);
    quant_transpose_kernel<<<dim3(N_DIM / 32, K_DIM / 32), dim3(32, 8), 0, stream>>>(W, wqt, mb);
    cast_bf16_kernel<<<4096, 256, 0, stream>>>(xb, xb_bf, (M_DIM * K_DIM) / 4);
    gemm_kernel<<<dim3(N_DIM / 128, M_DIM / 128), 256, 0, stream>>>(xb_bf, wqt, b, mb, out);
}